// Round 1
// 543.132 us; speedup vs baseline: 1.1330x; 1.1330x over previous
//
#include <hip/hip_runtime.h>
#include <hip/hip_bf16.h>
#include <stdint.h>

typedef float  f32x4   __attribute__((ext_vector_type(4)));
typedef short  short8  __attribute__((ext_vector_type(8)));
typedef short  short4v __attribute__((ext_vector_type(4)));

#define TOTAL 8192

// async global->LDS, 16B per lane; LDS dest = wave-uniform base + lane*16
__device__ __forceinline__ void dma16(const void* g, void* l) {
  __builtin_amdgcn_global_load_lds(
      (const __attribute__((address_space(1))) unsigned int*)g,
      (__attribute__((address_space(3))) unsigned int*)l,
      16, 0, 0);
}

// Wt[s][v][u_sw] = bf16(w_s[u][v] * 1/sqrt(512)) -- transpose + scale-fold + cvt.
// u_sw: 16B-chunk index XOR-swizzled with ((v>>1)&3) inside each 32-elem window.
// The linear B-DMA then lands original chunk c at LDS slot c ^ ((v>>1)&3); the
// b128 frag read XORs the same -> bank spread 8-way -> 2-way (free, m136).
__global__ __launch_bounds__(256) void prep_wt(
    const float* __restrict__ w0, const float* __restrict__ w1,
    const float* __restrict__ w2, const float* __restrict__ w3,
    __hip_bfloat16* __restrict__ wt) {
  __shared__ float T[64][65];
  const int s = blockIdx.z;
  const float* w = (s == 0) ? w0 : (s == 1) ? w1 : (s == 2) ? w2 : w3;
  const int u0 = blockIdx.y * 64, v0 = blockIdx.x * 64;
  const int tx = threadIdx.x & 63, ty = threadIdx.x >> 6;
#pragma unroll
  for (int k = 0; k < 16; ++k) {
    int r = ty * 16 + k;
    T[r][tx] = w[(size_t)(u0 + r) * 512 + v0 + tx];
  }
  __syncthreads();
  const float scale = 0.04419417382415922f;  // 1/sqrt(512)
  const int ksw_base = (tx & ~31) | (tx & 7);
  const int kch = (tx >> 3) & 3;
#pragma unroll
  for (int k = 0; k < 16; ++k) {
    int r = ty * 16 + k;                       // v-local
    int ksw = ksw_base | ((kch ^ ((r >> 1) & 3)) << 3);
    wt[((size_t)s << 18) + (size_t)(v0 + r) * 512 + u0 + ksw] =
        __float2bfloat16(T[tx][r] * scale);
  }
}

// One segment GEMM: rows = (n,j) n-major (row = n*D + j), M_d = 8192*D,
// K = 512 (u), N = 512 (v).  BM=64, BN=512 (full v -> x read exactly once),
// BK=32.  Pipelined: double-buffered As/Bs, ONE barrier per K-iter; next-tile
// A loads (HBM) + B DMA (L2) issued before the MFMA block so their latency
// hides under compute (T3-min + T14).
template <int D, int SEGOFF>
__device__ __forceinline__ void seg_gemm(
    const float* __restrict__ x, const __hip_bfloat16* __restrict__ wt,
    float* __restrict__ out, int rt) {
  constexpr int BM = 64, BK = 32, LDA = BK + 8;  // 80B row stride: 2-way-free b64 frag reads
  constexpr int CHUNK = BK * D;                  // fp32 elems per n per K-iter
  constexpr int ASZ = BM * LDA;                  // 2560 bf16 = 5120 B per buffer
  constexpr int BSZ = 512 * BK;                  // 16384 bf16 = 32768 B per buffer
  constexpr int NPF = (D == 1) ? 2 : 3;          // float4 prefetch slots per thread
  extern __shared__ char smem[];
  __hip_bfloat16* As = (__hip_bfloat16*)smem;                  // 2 x 5120 B
  __hip_bfloat16* Bs = (__hip_bfloat16*)(smem + 2 * ASZ * 2);  // 2 x 32768 B

  const int tid  = threadIdx.x;
  const int lane = tid & 63;
  const int wv   = tid >> 6;
  const int row0 = rt * BM;
  const int nF   = row0 / D;
  const int nL   = (row0 + BM - 1) / D;
  const int F4   = ((nL - nF + 1) * CHUNK) >> 2;  // float4 count to sweep
  const int q  = lane >> 4, cl = lane & 15;
  const int slotx = (q ^ ((cl >> 1) & 3)) << 3;   // swizzled B chunk, elem offset

  f32x4 acc[4][8] = {};

  auto loadA = [&](int e, int k0) -> float4 {
    int p4 = e << 2;
    int nb = p4 / CHUNK;            // compile-time-const divisor (magic mul)
    int p  = p4 - nb * CHUNK;
    int n  = nF + nb;
    // 16B-aligned: SEGOFF, k0*D, p all %4==0
    return *(const float4*)(x + (size_t)n * TOTAL + SEGOFF + k0 * D + p);
  };
  auto storeA = [&](__hip_bfloat16* Ab, int e, float4 vv) {
    if (e >= F4) return;
    int p4 = e << 2;
    int nb = p4 / CHUNK;
    int p  = p4 - nb * CHUNK;
    int n  = nF + nb;
    if (D == 1) {
      int r = n - row0;
      if ((unsigned)r < (unsigned)BM) {
        __hip_bfloat16 tmp[4];
        tmp[0] = __float2bfloat16(vv.x); tmp[1] = __float2bfloat16(vv.y);
        tmp[2] = __float2bfloat16(vv.z); tmp[3] = __float2bfloat16(vv.w);
        *(short4v*)&Ab[r * LDA + p] = *(const short4v*)tmp;
      }
    } else {
      const float* vf = (const float*)&vv;
#pragma unroll
      for (int c = 0; c < 4; ++c) {
        int pc = p + c;
        int u  = pc / D;             // const divisor
        int j  = pc - u * D;
        int r  = n * D + j - row0;
        if ((unsigned)r < (unsigned)BM)
          Ab[r * LDA + u] = __float2bfloat16(vf[c]);
      }
    }
  };
  auto dmaB = [&](__hip_bfloat16* Bb, int k0) {
#pragma unroll
    for (int t8 = 0; t8 < 8; ++t8) {
      int i = wv * 8 + t8;                       // wave-uniform LDS chunk id
      int vrow = i * 16 + (lane >> 2);
      dma16(wt + (size_t)vrow * 512 + k0 + ((lane & 3) << 3), Bb + i * 512);
    }
  };

  // ---- prologue: stage K-tile 0 into buffer 0 ----
  for (int e = tid; e < F4; e += 256) storeA(As, e, loadA(e, 0));
  dmaB(Bs, 0);
  __syncthreads();

#pragma unroll 2
  for (int t = 0; t < 16; ++t) {
    const int cur = t & 1;
    const int k0n = ((t + 1) & 15) * BK;  // wrap: iter 15 prefetches tile 0 (dead, harmless)
    __hip_bfloat16* Ac = As + cur * ASZ;
    __hip_bfloat16* Bc = Bs + cur * BSZ;
    __hip_bfloat16* An = As + (cur ^ 1) * ASZ;
    __hip_bfloat16* Bn = Bs + (cur ^ 1) * BSZ;

    // ---- issue next-tile A loads (HBM->regs) + B DMA (L2->LDS), branchless ----
    float4 pf[NPF];
#pragma unroll
    for (int i = 0; i < NPF; ++i) {
      int e = tid + (i << 8);
      pf[i] = loadA(e < F4 ? e : 0, k0n);  // clamp address, keep load unconditional
    }
    dmaB(Bn, k0n);

    // ---- compute current tile: 4 A-frags + 8 B-frags -> 32 MFMA ----
    short8 afr[4];
#pragma unroll
    for (int mi = 0; mi < 4; ++mi) {
      const __hip_bfloat16* pa = Ac + (mi * 16 + cl) * LDA + q * 8;
      short4v lo = *(const short4v*)pa;
      short4v hi = *(const short4v*)(pa + 4);
      afr[mi] = __builtin_shufflevector(lo, hi, 0, 1, 2, 3, 4, 5, 6, 7);
    }
#pragma unroll
    for (int ni = 0; ni < 8; ++ni) {
      const short8 bfr = *(const short8*)(Bc + (wv * 128 + ni * 16 + cl) * BK + slotx);
#pragma unroll
      for (int mi = 0; mi < 4; ++mi)
        acc[mi][ni] = __builtin_amdgcn_mfma_f32_16x16x32_bf16(afr[mi], bfr, acc[mi][ni], 0, 0, 0);
    }

    // ---- cvt + scatter next-tile A into LDS (waits only on pf, DMA stays in flight) ----
#pragma unroll
    for (int i = 0; i < NPF; ++i) storeA(An, tid + (i << 8), pf[i]);
    __syncthreads();  // single drain point per K-iter
  }

  // ---- epilogue: C/D layout col=lane&15, row=(lane>>4)*4+reg (m89-verified) ----
#pragma unroll
  for (int mi = 0; mi < 4; ++mi) {
#pragma unroll
    for (int ni = 0; ni < 8; ++ni) {
#pragma unroll
      for (int rg = 0; rg < 4; ++rg) {
        int R = row0 + mi * 16 + q * 4 + rg;
        int n = R / D;
        int j = R - n * D;
        int v = wv * 128 + ni * 16 + cl;
        out[(size_t)n * TOTAL + SEGOFF + v * D + j] = acc[mi][ni][rg];
      }
    }
  }
}

// Row-tile counts: d=1:128, d=3:384, d=5:640, d=7:896  => 2048 blocks total
__global__ __launch_bounds__(256, 2) void linear_main(
    const float* __restrict__ x, const __hip_bfloat16* __restrict__ wt,
    float* __restrict__ out) {
  int bx = blockIdx.x;
  if (bx < 128)        seg_gemm<1, 0>   (x, wt,             out, bx);
  else if (bx < 512)   seg_gemm<3, 512> (x, wt + (1 << 18), out, bx - 128);
  else if (bx < 1152)  seg_gemm<5, 2048>(x, wt + (2 << 18), out, bx - 512);
  else                 seg_gemm<7, 4608>(x, wt + (3 << 18), out, bx - 1152);
}

#define LDS_BYTES 75776  // 2*(5120 + 32768)

extern "C" void kernel_launch(void* const* d_in, const int* in_sizes, int n_in,
                              void* d_out, int out_size, void* d_ws, size_t ws_size,
                              hipStream_t stream) {
  const float* x  = (const float*)d_in[0];
  const float* w0 = (const float*)d_in[1];
  const float* w1 = (const float*)d_in[2];
  const float* w2 = (const float*)d_in[3];
  const float* w3 = (const float*)d_in[4];
  __hip_bfloat16* wt = (__hip_bfloat16*)d_ws;  // needs 2 MB scratch
  float* out = (float*)d_out;

  // dynamic LDS > 64 KB needs the opt-in attribute (host-side, capture-safe)
  hipFuncSetAttribute((const void*)linear_main,
                      hipFuncAttributeMaxDynamicSharedMemorySize, LDS_BYTES);

  hipLaunchKernelGGL(prep_wt, dim3(8, 8, 4), dim3(256), 0, stream,
                     w0, w1, w2, w3, wt);
  hipLaunchKernelGGL(linear_main, dim3(2048), dim3(256), LDS_BYTES, stream,
                     x, wt, out);
}

// Round 2
// 530.192 us; speedup vs baseline: 1.1606x; 1.0244x over previous
//
#include <hip/hip_runtime.h>
#include <hip/hip_bf16.h>
#include <stdint.h>

typedef float  f32x4   __attribute__((ext_vector_type(4)));
typedef short  short8  __attribute__((ext_vector_type(8)));
typedef short  short4v __attribute__((ext_vector_type(4)));

#define TOTAL 8192

// async global->LDS, 16B per lane; LDS dest = wave-uniform base + lane*16
__device__ __forceinline__ void dma16(const void* g, void* l) {
  __builtin_amdgcn_global_load_lds(
      (const __attribute__((address_space(1))) unsigned int*)g,
      (__attribute__((address_space(3))) unsigned int*)l,
      16, 0, 0);
}

// counted waits; sched_barrier stops register-only ops hoisting past (rule #18)
#define WAITV(N) do { asm volatile("s_waitcnt vmcnt(" #N ")" ::: "memory"); \
                      __builtin_amdgcn_sched_barrier(0); } while (0)
#define WAITL0() asm volatile("s_waitcnt lgkmcnt(0)" ::: "memory")
#define BAR()    __builtin_amdgcn_s_barrier()

// Wt[s][v][u_sw] = bf16(w_s[u][v] * 1/sqrt(512)) -- transpose + scale-fold + cvt.
// u-chunk (8 elems) index XOR-swizzled with ((v>>1)&3) inside each 32-elem window
// (same contract as round 1, verified passing). Vectorized 16B stores.
__global__ __launch_bounds__(256) void prep_wt(
    const float* __restrict__ w0, const float* __restrict__ w1,
    const float* __restrict__ w2, const float* __restrict__ w3,
    __hip_bfloat16* __restrict__ wt) {
  __shared__ float T[64][65];
  const int s = blockIdx.z;
  const float* w = (s == 0) ? w0 : (s == 1) ? w1 : (s == 2) ? w2 : w3;
  const int u0 = blockIdx.y * 64, v0 = blockIdx.x * 64;
  const int tx = threadIdx.x & 63, ty = threadIdx.x >> 6;
#pragma unroll
  for (int k = 0; k < 16; ++k) {
    int r = ty * 16 + k;
    T[r][tx] = w[(size_t)(u0 + r) * 512 + v0 + tx];
  }
  __syncthreads();
  const float scale = 0.04419417382415922f;  // 1/sqrt(512)
#pragma unroll
  for (int rep = 0; rep < 2; ++rep) {
    int idx = rep * 256 + threadIdx.x;   // 512 chunks per 64x64 tile
    int r   = idx >> 3;                  // v-local 0..63
    int kc  = idx & 7;                   // u-chunk 0..7
    int ksw = (kc & 4) | ((kc & 3) ^ ((r >> 1) & 3));
    __hip_bfloat16 t8[8];
#pragma unroll
    for (int i = 0; i < 8; ++i) t8[i] = __float2bfloat16(T[kc * 8 + i][r] * scale);
    *(short8*)&wt[((size_t)s << 18) + (size_t)(v0 + r) * 512 + u0 + ksw * 8] =
        *(const short8*)t8;
  }
}

// One segment GEMM: rows = (n,j) n-major (row = n*D + j), M_d = 8192*D,
// K = 512 (u), N = 512 (v).  BM=64, BN=512 (full v -> x read exactly once),
// BK=32.  T3+T4 pipeline: raw s_barrier (As handoff only) + COUNTED vmcnt;
// B is wave-private (wave wv DMAs and reads rows [wv*128,+128)) so B-DMAs
// stay in flight across barriers; A-loads get 2 iters of latency tolerance.
// Per-iter VMEM issue order: D(t+1)[8], A(t+2)[3]:
//   vmcnt(14) => D(t) retired (newer: A(t+1)3 + D(t+1)8 + A(t+2)3)
//   vmcnt(11) => A(t+1) retired (newer: D(t+1)8 + A(t+2)3)
template <int D, int SEGOFF>
__device__ __forceinline__ void seg_gemm(
    const float* __restrict__ x, const __hip_bfloat16* __restrict__ wt,
    float* __restrict__ out, int rt) {
  constexpr int BM = 64, BK = 32, LDA = BK + 8;  // 80B row stride
  constexpr int CHUNK = BK * D;                  // fp32 elems per n per K-iter
  constexpr int ASZ = BM * LDA;                  // 2560 bf16 per buffer
  constexpr int BSZ = 512 * BK;                  // 16384 bf16 per buffer
  constexpr int NPF = (D == 1) ? 2 : 3;          // float4 slots per thread
  extern __shared__ char smem[];
  __hip_bfloat16* As0 = (__hip_bfloat16*)smem;
  __hip_bfloat16* As1 = As0 + ASZ;
  __hip_bfloat16* Bs0 = As0 + 2 * ASZ;
  __hip_bfloat16* Bs1 = Bs0 + BSZ;

  const int tid  = threadIdx.x;
  const int lane = tid & 63;
  const int wv   = tid >> 6;
  const int row0 = rt * BM;
  const int nF   = row0 / D;
  const int nL   = (row0 + BM - 1) / D;
  const int F4   = ((nL - nF + 1) * CHUNK) >> 2;
  const int q  = lane >> 4, cl = lane & 15;
  const int slotx = (q ^ ((cl >> 1) & 3)) << 3;  // swizzled B chunk elem offset

  // ---- k0-invariant A staging addresses + LDS scatter offsets (hoisted) ----
  const float* abase[NPF];
  int aoff[NPF][4];
#pragma unroll
  for (int i = 0; i < NPF; ++i) {
    int e  = tid + (i << 8);
    int ec = e < F4 ? e : 0;             // clamp: keep load address valid
    int p4 = ec << 2;
    int nb = p4 / CHUNK;                 // compile-time-const divisor
    int p  = p4 - nb * CHUNK;
    int n  = nF + nb;
    abase[i] = x + (size_t)n * TOTAL + SEGOFF + p;   // + k0*D per iter
    if (D == 1) {
      aoff[i][0] = (e < F4) ? ((n - row0) * LDA + p) : -1;
    } else {
#pragma unroll
      for (int c = 0; c < 4; ++c) {
        int pc = p + c;
        int u  = pc / D;
        int j  = pc - u * D;
        int r  = n * D + j - row0;
        aoff[i][c] = (e < F4 && (unsigned)r < (unsigned)BM) ? (r * LDA + u) : -1;
      }
    }
  }

  f32x4 acc[4][8] = {};

  auto issueA = [&](float4 (&pf)[NPF], int k0) {
#pragma unroll
    for (int i = 0; i < NPF; ++i)
      pf[i] = *(const float4*)(abase[i] + k0 * D);
  };
  auto storeA = [&](__hip_bfloat16* Ab, float4 (&pf)[NPF]) {
#pragma unroll
    for (int i = 0; i < NPF; ++i) {
      if (D == 1) {
        if (aoff[i][0] >= 0) {
          __hip_bfloat16 t4[4];
          t4[0] = __float2bfloat16(pf[i].x); t4[1] = __float2bfloat16(pf[i].y);
          t4[2] = __float2bfloat16(pf[i].z); t4[3] = __float2bfloat16(pf[i].w);
          *(short4v*)&Ab[aoff[i][0]] = *(const short4v*)t4;
        }
      } else {
        const float* vf = (const float*)&pf[i];
#pragma unroll
        for (int c = 0; c < 4; ++c)
          if (aoff[i][c] >= 0) Ab[aoff[i][c]] = __float2bfloat16(vf[c]);
      }
    }
  };
  auto dmaB = [&](__hip_bfloat16* Bb, int k0) {
#pragma unroll
    for (int t8 = 0; t8 < 8; ++t8) {
      int i = wv * 8 + t8;                        // wave-uniform LDS chunk
      int vrow = i * 16 + (lane >> 2);
      dma16(wt + (size_t)vrow * 512 + k0 + ((lane & 3) << 3), Bb + i * 512);
    }
  };
  auto compute = [&](const __hip_bfloat16* Ac, const __hip_bfloat16* Bc) {
    short8 afr[4];
#pragma unroll
    for (int mi = 0; mi < 4; ++mi) {
      const __hip_bfloat16* pa = Ac + (mi * 16 + cl) * LDA + q * 8;
      short4v lo = *(const short4v*)pa;
      short4v hi = *(const short4v*)(pa + 4);
      afr[mi] = __builtin_shufflevector(lo, hi, 0, 1, 2, 3, 4, 5, 6, 7);
    }
#pragma unroll
    for (int ni = 0; ni < 8; ++ni) {
      const short8 bfr = *(const short8*)(Bc + (wv * 128 + ni * 16 + cl) * BK + slotx);
#pragma unroll
      for (int mi = 0; mi < 4; ++mi)
        acc[mi][ni] = __builtin_amdgcn_mfma_f32_16x16x32_bf16(afr[mi], bfr, acc[mi][ni], 0, 0, 0);
    }
  };

  // ---- prologue: issue A(0), D(0), A(1); stage As0; enter steady state ----
  float4 pf_a[NPF], pf_b[NPF];
  issueA(pf_a, 0);                       // A(0)
  dmaB(Bs0, 0);                          // D(0)
  issueA(pf_b, BK);                      // A(1)
  WAITV(11);                             // A(0) retired
  storeA(As0, pf_a);
  WAITL0(); BAR();
  // outstanding: [D(0)x8, A(1)x3] == steady-state entry

  for (int t = 0; t < 16; t += 2) {
    // ---- even: compute As0/Bs0; stage As1/Bs1; consume pf_b, issue pf_a ----
    dmaB(Bs1, ((t + 1) & 15) * BK);      // D(t+1)
    issueA(pf_a, ((t + 2) & 15) * BK);   // A(t+2)
    WAITV(14);                           // D(t) in LDS (wave-private B)
    compute(As0, Bs0);
    WAITV(11);                           // A(t+1) arrived
    storeA(As1, pf_b);
    WAITL0(); BAR();                     // As1 published; D(t+1) still in flight
    // ---- odd: mirror ----
    dmaB(Bs0, ((t + 2) & 15) * BK);      // D(t+2)
    issueA(pf_b, ((t + 3) & 15) * BK);   // A(t+3)
    WAITV(14);                           // D(t+1) in LDS
    compute(As1, Bs1);
    WAITV(11);                           // A(t+2) arrived
    storeA(As0, pf_a);
    WAITL0(); BAR();
  }
  // drain dead wrap loads: outstanding DMA writes to LDS after endpgm could
  // land in a reallocated workgroup's LDS
  asm volatile("s_waitcnt vmcnt(0)" ::: "memory");

  // ---- epilogue: C/D layout col=lane&15, row=(lane>>4)*4+reg (m89-verified) ----
#pragma unroll
  for (int mi = 0; mi < 4; ++mi) {
#pragma unroll
    for (int ni = 0; ni < 8; ++ni) {
#pragma unroll
      for (int rg = 0; rg < 4; ++rg) {
        int R = row0 + mi * 16 + q * 4 + rg;
        int n = R / D;
        int j = R - n * D;
        int v = wv * 128 + ni * 16 + cl;
        out[(size_t)n * TOTAL + SEGOFF + v * D + j] = acc[mi][ni][rg];
      }
    }
  }
}

// Row-tile counts: d=1:128, d=3:384, d=5:640, d=7:896  => 2048 blocks total
__global__ __launch_bounds__(256, 2) void linear_main(
    const float* __restrict__ x, const __hip_bfloat16* __restrict__ wt,
    float* __restrict__ out) {
  int bx = blockIdx.x;
  if (bx < 128)        seg_gemm<1, 0>   (x, wt,             out, bx);
  else if (bx < 512)   seg_gemm<3, 512> (x, wt + (1 << 18), out, bx - 128);
  else if (bx < 1152)  seg_gemm<5, 2048>(x, wt + (2 << 18), out, bx - 512);
  else                 seg_gemm<7, 4608>(x, wt + (3 << 18), out, bx - 1152);
}

#define LDS_BYTES 75776  // 2*(5120 + 32768)

extern "C" void kernel_launch(void* const* d_in, const int* in_sizes, int n_in,
                              void* d_out, int out_size, void* d_ws, size_t ws_size,
                              hipStream_t stream) {
  const float* x  = (const float*)d_in[0];
  const float* w0 = (const float*)d_in[1];
  const float* w1 = (const float*)d_in[2];
  const float* w2 = (const float*)d_in[3];
  const float* w3 = (const float*)d_in[4];
  __hip_bfloat16* wt = (__hip_bfloat16*)d_ws;  // 2 MB scratch
  float* out = (float*)d_out;

  hipFuncSetAttribute((const void*)linear_main,
                      hipFuncAttributeMaxDynamicSharedMemorySize, LDS_BYTES);

  hipLaunchKernelGGL(prep_wt, dim3(8, 8, 4), dim3(256), 0, stream,
                     w0, w1, w2, w3, wt);
  hipLaunchKernelGGL(linear_main, dim3(2048), dim3(256), LDS_BYTES, stream,
                     x, wt, out);
}

// Round 3
// 503.296 us; speedup vs baseline: 1.2227x; 1.0534x over previous
//
#include <hip/hip_runtime.h>
#include <hip/hip_bf16.h>
#include <stdint.h>

typedef float  f32x4   __attribute__((ext_vector_type(4)));
typedef short  short8  __attribute__((ext_vector_type(8)));
typedef short  short4v __attribute__((ext_vector_type(4)));

#define TOTAL 8192

// async global->LDS, 16B per lane; LDS dest = wave-uniform base + lane*16
__device__ __forceinline__ void dma16(const void* g, void* l) {
  __builtin_amdgcn_global_load_lds(
      (const __attribute__((address_space(1))) unsigned int*)g,
      (__attribute__((address_space(3))) unsigned int*)l,
      16, 0, 0);
}

// counted waits; sched_barrier stops register-only ops hoisting past (rule #18)
#define WAITV(N) do { asm volatile("s_waitcnt vmcnt(" #N ")" ::: "memory"); \
                      __builtin_amdgcn_sched_barrier(0); } while (0)
#define WAITL0() asm volatile("s_waitcnt lgkmcnt(0)" ::: "memory")
#define BAR()    __builtin_amdgcn_s_barrier()

// Wt[s][v][u_sw] = bf16(w_s[u][v] * 1/sqrt(512)) -- transpose + scale-fold + cvt.
// u-chunk (8 elems) index XOR-swizzled with ((v>>1)&3) inside each 32-elem window
// (contract verified passing rounds 1-2). Vectorized 16B stores.
__global__ __launch_bounds__(256) void prep_wt(
    const float* __restrict__ w0, const float* __restrict__ w1,
    const float* __restrict__ w2, const float* __restrict__ w3,
    __hip_bfloat16* __restrict__ wt) {
  __shared__ float T[64][65];
  const int s = blockIdx.z;
  const float* w = (s == 0) ? w0 : (s == 1) ? w1 : (s == 2) ? w2 : w3;
  const int u0 = blockIdx.y * 64, v0 = blockIdx.x * 64;
  const int tx = threadIdx.x & 63, ty = threadIdx.x >> 6;
#pragma unroll
  for (int k = 0; k < 16; ++k) {
    int r = ty * 16 + k;
    T[r][tx] = w[(size_t)(u0 + r) * 512 + v0 + tx];
  }
  __syncthreads();
  const float scale = 0.04419417382415922f;  // 1/sqrt(512)
#pragma unroll
  for (int rep = 0; rep < 2; ++rep) {
    int idx = rep * 256 + threadIdx.x;   // 512 chunks per 64x64 tile
    int r   = idx >> 3;                  // v-local 0..63
    int kc  = idx & 7;                   // u-chunk 0..7
    int ksw = (kc & 4) | ((kc & 3) ^ ((r >> 1) & 3));
    __hip_bfloat16 t8[8];
#pragma unroll
    for (int i = 0; i < 8; ++i) t8[i] = __float2bfloat16(T[kc * 8 + i][r] * scale);
    *(short8*)&wt[((size_t)s << 18) + (size_t)(v0 + r) * 512 + u0 + ksw * 8] =
        *(const short8*)t8;
  }
}

// One segment GEMM: rows = (n,j) n-major (row = n*D + j), K = 512 (u), N = 512 (v).
// BM=128, BN=512 (full v -> x read exactly once), BK=32, 512 threads = 8 waves.
// Wave wv owns v-strip [wv*64, wv*64+64) for ALL 128 rows: acc[8][4].
// B is wave-private (wave DMAs + reads only its strip) -> B-DMAs never need a
// barrier and stay in flight across iters (counted vmcnt, T3+T4); only the
// cooperative A tile is barrier-protected.
// Per-iter VMEM issue: D(t+1)[4], A(t+2)[NPF]:
//   steady outstanding before iter = 4+NPF; after issue = 8+2*NPF
//   WAITV(4+2*NPF) => D(t) retired; WAITV(4+NPF) => A(t+1) retired
template <int D, int SEGOFF>
__device__ __forceinline__ void seg_gemm(
    const float* __restrict__ x, const __hip_bfloat16* __restrict__ wt,
    float* __restrict__ out, int rt) {
  constexpr int BM = 128, BK = 32, LDA = BK + 8;  // 80B row stride: 2-way-free b64 reads
  constexpr int CHUNK = BK * D;                   // fp32 elems per n per K-iter
  constexpr int ASZ = BM * LDA;                   // 5120 bf16 = 10240 B per buffer
  constexpr int BSZ = 512 * BK;                   // 16384 bf16 = 32768 B per buffer
  constexpr int NPF = (D == 1) ? 2 : 3;           // float4 slots per thread (512 thr)
  extern __shared__ char smem[];
  __hip_bfloat16* As0 = (__hip_bfloat16*)smem;
  __hip_bfloat16* As1 = As0 + ASZ;
  __hip_bfloat16* Bs0 = As0 + 2 * ASZ;
  __hip_bfloat16* Bs1 = Bs0 + BSZ;

  const int tid  = threadIdx.x;          // 0..511
  const int lane = tid & 63;
  const int wv   = tid >> 6;             // 0..7: v-strip owner
  const int row0 = rt * BM;
  const int nF   = row0 / D;
  const int nL   = (row0 + BM - 1) / D;
  const int F4   = ((nL - nF + 1) * CHUNK) >> 2;
  const int q  = lane >> 4, cl = lane & 15;
  const int slotx = (q ^ ((cl >> 1) & 3)) << 3;   // swizzled B chunk elem offset

  // ---- k0-invariant A staging addresses + LDS scatter offsets (hoisted) ----
  const float* abase[NPF];
  int aoff[NPF][4];
#pragma unroll
  for (int i = 0; i < NPF; ++i) {
    int e  = tid + (i << 9);
    int ec = e < F4 ? e : 0;             // clamp: keep load address valid
    int p4 = ec << 2;
    int nb = p4 / CHUNK;                 // compile-time-const divisor
    int p  = p4 - nb * CHUNK;
    int n  = nF + nb;
    abase[i] = x + (size_t)n * TOTAL + SEGOFF + p;   // + k0*D per iter
    if (D == 1) {
      aoff[i][0] = (e < F4) ? ((n - row0) * LDA + p) : -1;
    } else {
#pragma unroll
      for (int c = 0; c < 4; ++c) {
        int pc = p + c;
        int u  = pc / D;
        int j  = pc - u * D;
        int r  = n * D + j - row0;
        aoff[i][c] = (e < F4 && (unsigned)r < (unsigned)BM) ? (r * LDA + u) : -1;
      }
    }
  }

  f32x4 acc[8][4] = {};

  auto issueA = [&](float4 (&pf)[NPF], int k0) {
#pragma unroll
    for (int i = 0; i < NPF; ++i)
      pf[i] = *(const float4*)(abase[i] + k0 * D);
  };
  auto storeA = [&](__hip_bfloat16* Ab, float4 (&pf)[NPF]) {
#pragma unroll
    for (int i = 0; i < NPF; ++i) {
      if (D == 1) {
        if (aoff[i][0] >= 0) {
          __hip_bfloat16 t4[4];
          t4[0] = __float2bfloat16(pf[i].x); t4[1] = __float2bfloat16(pf[i].y);
          t4[2] = __float2bfloat16(pf[i].z); t4[3] = __float2bfloat16(pf[i].w);
          *(short4v*)&Ab[aoff[i][0]] = *(const short4v*)t4;
        }
      } else {
        const float* vf = (const float*)&pf[i];
#pragma unroll
        for (int c = 0; c < 4; ++c)
          if (aoff[i][c] >= 0) Ab[aoff[i][c]] = __float2bfloat16(vf[c]);
      }
    }
  };
  auto dmaB = [&](__hip_bfloat16* Bb, int k0) {
#pragma unroll
    for (int t4 = 0; t4 < 4; ++t4) {
      int i = wv * 4 + t4;                        // wave-private chunk (16 v-rows)
      int vrow = i * 16 + (lane >> 2);
      dma16(wt + (size_t)vrow * 512 + k0 + ((lane & 3) << 3), Bb + i * 512);
    }
  };
  auto compute = [&](const __hip_bfloat16* Ac, const __hip_bfloat16* Bc) {
    short8 afr[8];
#pragma unroll
    for (int mi = 0; mi < 8; ++mi) {
      const __hip_bfloat16* pa = Ac + (mi * 16 + cl) * LDA + q * 8;
      short4v lo = *(const short4v*)pa;
      short4v hi = *(const short4v*)(pa + 4);
      afr[mi] = __builtin_shufflevector(lo, hi, 0, 1, 2, 3, 4, 5, 6, 7);
    }
#pragma unroll
    for (int ni = 0; ni < 4; ++ni) {
      const short8 bfr = *(const short8*)(Bc + (wv * 64 + ni * 16 + cl) * BK + slotx);
#pragma unroll
      for (int mi = 0; mi < 8; ++mi)
        acc[mi][ni] = __builtin_amdgcn_mfma_f32_16x16x32_bf16(afr[mi], bfr, acc[mi][ni], 0, 0, 0);
    }
  };

  // ---- prologue: issue A(0), D(0), A(1); stage As0 ----
  float4 pf_a[NPF], pf_b[NPF];
  issueA(pf_a, 0);                       // A(0)
  dmaB(Bs0, 0);                          // D(0)
  issueA(pf_b, BK);                      // A(1)
  if constexpr (NPF == 3) { WAITV(7); } else { WAITV(6); }   // A(0) retired
  storeA(As0, pf_a);
  WAITL0(); BAR();
  // outstanding: [D(0)x4, A(1)xNPF]

  for (int t = 0; t < 16; t += 2) {
    // ---- even: compute As0/Bs0 ----
    dmaB(Bs1, ((t + 1) & 15) * BK);      // D(t+1)
    issueA(pf_a, ((t + 2) & 15) * BK);   // A(t+2)
    if constexpr (NPF == 3) { WAITV(10); } else { WAITV(8); }  // D(t) in LDS
    compute(As0, Bs0);
    if constexpr (NPF == 3) { WAITV(7); } else { WAITV(6); }   // A(t+1) arrived
    storeA(As1, pf_b);
    WAITL0(); BAR();
    // ---- odd: mirror ----
    dmaB(Bs0, ((t + 2) & 15) * BK);      // D(t+2)
    issueA(pf_b, ((t + 3) & 15) * BK);   // A(t+3)
    if constexpr (NPF == 3) { WAITV(10); } else { WAITV(8); }  // D(t+1) in LDS
    compute(As1, Bs1);
    if constexpr (NPF == 3) { WAITV(7); } else { WAITV(6); }   // A(t+2) arrived
    storeA(As0, pf_a);
    WAITL0(); BAR();
  }
  // drain dead wrap prefetches before reusing LDS (DMA writes land in Bs region)
  asm volatile("s_waitcnt vmcnt(0)" ::: "memory");
  BAR();

  // ---- coalesced epilogue via LDS transpose ----
  // Chunk = 32 consecutive R-rows (= acc[2ch],acc[2ch+1]); Cs[v][36] fp32,
  // R-minor so acc f32x4 (4 consecutive R) writes as ds_write_b128.
  // Read-out emits contiguous out rows: c = v*D+j in [0,512*D) per full n.
  float* Cs = (float*)smem;              // 512*36*4 = 73728 B <= 86016
#pragma unroll
  for (int ch = 0; ch < 4; ++ch) {
    const int Glo = row0 + ch * 32;      // chunk covers G = n*D+j in [Glo,Glo+32)
#pragma unroll
    for (int mm = 0; mm < 2; ++mm) {
      const int r0 = mm * 16 + q * 4;    // local row base (rg quad)
#pragma unroll
      for (int ni = 0; ni < 4; ++ni) {
        const int v = wv * 64 + ni * 16 + cl;
        *(f32x4*)&Cs[v * 36 + r0] = acc[ch * 2 + mm][ni];
      }
    }
    WAITL0(); BAR();
    const int n0 = Glo / D, n1 = (Glo + 31) / D;
    for (int n = n0; n <= n1; ++n) {
      int jlo = Glo - n * D;       if (jlo < 0) jlo = 0;
      int jhi = Glo + 32 - n * D;  if (jhi > D) jhi = D;
      float* orow = out + (size_t)n * TOTAL + SEGOFF;
      if (jlo == 0 && jhi == D) {
        // interior n: full row, contiguous float4 stores
        const int rb = n * D - Glo;
        for (int c4 = tid; c4 < 128 * D; c4 += 512) {
          int c = c4 << 2;
          float4 f;
          float* fp = (float*)&f;
#pragma unroll
          for (int k = 0; k < 4; ++k) {
            int cc = c + k;
            int v = cc / D;                // const divisor
            int j = cc - v * D;
            fp[k] = Cs[v * 36 + rb + j];
          }
          *(float4*)&orow[c] = f;
        }
      } else {
        // border n (j-range split across chunks/blocks): scalar stores
        const int nj = jhi - jlo;
        for (int e = tid; e < nj * 512; e += 512) {
          int j = jlo + (e >> 9);
          int v = e & 511;
          orow[v * D + j] = Cs[v * 36 + (n * D + j - Glo)];
        }
      }
    }
    BAR();  // reads done before next chunk overwrites Cs
  }
}

// Blocks per seg (BM=128): d=1:64, d=3:192, d=5:320, d=7:448 => 1024 total.
// T1 chunked XCD swizzle: XCD c (= bx%8) gets contiguous work ids [c*128,(c+1)*128)
// -> same-segment blocks share their wt panel in one XCD's L2. Bijective (1024%8==0).
__global__ __launch_bounds__(512, 2) void linear_main(
    const float* __restrict__ x, const __hip_bfloat16* __restrict__ wt,
    float* __restrict__ out) {
  int bx  = blockIdx.x;
  int wid = (bx & 7) * 128 + (bx >> 3);
  if (wid < 64)        seg_gemm<1, 0>   (x, wt,             out, wid);
  else if (wid < 256)  seg_gemm<3, 512> (x, wt + (1 << 18), out, wid - 64);
  else if (wid < 576)  seg_gemm<5, 2048>(x, wt + (2 << 18), out, wid - 256);
  else                 seg_gemm<7, 4608>(x, wt + (3 << 18), out, wid - 576);
}

#define LDS_BYTES 86016  // 2*10240 (As) + 2*32768 (Bs); epilogue Cs=73728 fits

extern "C" void kernel_launch(void* const* d_in, const int* in_sizes, int n_in,
                              void* d_out, int out_size, void* d_ws, size_t ws_size,
                              hipStream_t stream) {
  const float* x  = (const float*)d_in[0];
  const float* w0 = (const float*)d_in[1];
  const float* w1 = (const float*)d_in[2];
  const float* w2 = (const float*)d_in[3];
  const float* w3 = (const float*)d_in[4];
  __hip_bfloat16* wt = (__hip_bfloat16*)d_ws;  // 2 MB scratch
  float* out = (float*)d_out;

  hipFuncSetAttribute((const void*)linear_main,
                      hipFuncAttributeMaxDynamicSharedMemorySize, LDS_BYTES);

  hipLaunchKernelGGL(prep_wt, dim3(8, 8, 4), dim3(256), 0, stream,
                     w0, w1, w2, w3, wt);
  hipLaunchKernelGGL(linear_main, dim3(1024), dim3(512), LDS_BYTES, stream,
                     x, wt, out);
}